// Round 2
// baseline (5693.121 us; speedup 1.0000x reference)
//
#include <hip/hip_runtime.h>
#include <hip/hip_bf16.h>
#include <stdint.h>
#include <math.h>

#define NBATCH 512
#define NS 256
#define NE 128
#define NH 128
#define NSTEPS 255
#define NEGINF -1e8f

// ---------------- threefry2x32, exactly as JAX lowers it ----------------
__device__ __forceinline__ uint32_t rotl32(uint32_t x, uint32_t r) {
  return (x << r) | (x >> (32u - r));
}

__device__ __forceinline__ void tf2x32(uint32_t k0, uint32_t k1,
                                       uint32_t x0, uint32_t x1,
                                       uint32_t& o0, uint32_t& o1) {
  uint32_t ks2 = k0 ^ k1 ^ 0x1BD11BDAu;
  x0 += k0; x1 += k1;
#define TF_R4(a,b,c,d) \
  x0 += x1; x1 = rotl32(x1,a); x1 ^= x0; \
  x0 += x1; x1 = rotl32(x1,b); x1 ^= x0; \
  x0 += x1; x1 = rotl32(x1,c); x1 ^= x0; \
  x0 += x1; x1 = rotl32(x1,d); x1 ^= x0;
  TF_R4(13,15,26,6)   x0 += k1;  x1 += ks2 + 1u;
  TF_R4(17,29,16,24)  x0 += ks2; x1 += k0 + 2u;
  TF_R4(13,15,26,6)   x0 += k0;  x1 += k1 + 3u;
  TF_R4(17,29,16,24)  x0 += k1;  x1 += ks2 + 4u;
  TF_R4(13,15,26,6)   x0 += ks2; x1 += k0 + 5u;
#undef TF_R4
  o0 = x0; o1 = x1;
}

// fast accurate tanh: exp2 with split-constant arg + IEEE divide (~1e-7 abs)
__device__ __forceinline__ float fast_tanh(float x) {
  const float Chi = 2.8853900432586670f;      // float(2*log2(e))
  const float Clo = 3.8519259822379735e-08f;  // residual
  float m = fmaf(x, Chi, x * Clo);
  float t = exp2f(m);                          // v_exp_f32
  return 1.0f - 2.0f / (t + 1.0f);
}

struct MainSh {
  float  query[NE];
  float  qq[NH];
  float  hbar[NE];
  float  inith[NE];
  float  hcur[NE];
  alignas(16) double vvd[NH];
  float  logitArr[NS];
  float  maskArr[NS];
  uint2  keyL[NSTEPS];
  float  meanv[NE];
  float  redV[4];
  int    redI[4];
  double redS[4];
  int    idxSh;
};

struct PreSh {
  float cvS[NS][33];   // cv[:, e0:e0+32], padded stride 33 (conflict-free)
  float wS[32][NH];    // Wref[e0:e0+32, :]
};

__global__ __launch_bounds__(256, 2)
void decoder_kernel(const float* __restrict__ cv,
                    const float* __restrict__ mask_in,
                    const float* __restrict__ liw,
                    const float* __restrict__ Wc,
                    const float* __restrict__ bc,
                    const float* __restrict__ Wv,
                    const float* __restrict__ bv,
                    const float* __restrict__ Wq,
                    const float* __restrict__ Wref,
                    const float* __restrict__ vvec,
                    float* __restrict__ out) {
  const int b = blockIdx.x;
  const int t = threadIdx.x;
  const int b256 = b << 8;

  __shared__ union { PreSh pre; MainSh m; } sh;

  // ---------- Phase 1: ref[t][h] = sum_e cv[b][t][e] * Wref[e][h] ----------
  float refr[NH];
#pragma unroll
  for (int h = 0; h < NH; ++h) refr[h] = 0.0f;

  for (int ec = 0; ec < 4; ++ec) {
    const int e0 = ec * 32;
    __syncthreads();
    for (int i = t; i < 32 * NH; i += 256) {
      int r = i >> 7, h = i & 127;
      sh.pre.wS[r][h] = Wref[(e0 + r) * NH + h];
    }
    for (int i = t; i < NS * 32; i += 256) {
      int s = i >> 5, j = i & 31;
      sh.pre.cvS[s][j] = cv[((size_t)b256 + s) * NE + e0 + j];
    }
    __syncthreads();
#pragma unroll
    for (int hc = 0; hc < 16; ++hc) {
      double a[8] = {0,0,0,0,0,0,0,0};
      for (int e = 0; e < 32; ++e) {
        double cd = (double)sh.pre.cvS[t][e];
#pragma unroll
        for (int j = 0; j < 8; ++j)
          a[j] += cd * (double)sh.pre.wS[e][hc * 8 + j];
      }
#pragma unroll
      for (int j = 0; j < 8; ++j) refr[hc * 8 + j] += (float)a[j];
    }
  }
  __syncthreads();  // pre region dead; m region live from here

  // ---------- Phase 2: prologue ----------
  if (t < NSTEPS) {
    // partitionable (fold-like) split: keys[i] = threefry2x32(key, hi=0, lo=i)
    uint32_t o0, o1;
    tf2x32(0u, 42u, 0u, (uint32_t)t, o0, o1);
    sh.m.keyL[t] = make_uint2(o0, o1);
  }
  if (t < NH) sh.m.vvd[t] = (double)vvec[t];
  sh.m.maskArr[t] = (mask_in[(size_t)b256 + t] > 0.0f || t == 0) ? 1.0f : 0.0f;
  if (t < NE) {
    double s64 = 0.0;
    for (int s = 0; s < NS; ++s) s64 += (double)cv[((size_t)b256 + s) * NE + t];
    sh.m.meanv[t] = (float)(s64 * (1.0 / 256.0));
  }
  __syncthreads();
  if (t < NE) {
    double acc = 0.0;
    for (int e = 0; e < NE; ++e)
      acc += (double)sh.m.meanv[e] * (double)Wc[e * NE + t];
    float hb = (float)acc + bc[t];                // h_bar = mean@Wc + bc
    sh.m.hbar[t] = hb;
    double acc2 = 0.0;
    for (int k = 0; k < 2 * NE; ++k)
      acc2 += (double)liw[k] * (double)Wv[k * NE + t];
    float r0 = (float)acc2 + bv[t];               // rest0 = liw@Wv + bv
    sh.m.query[t] = hb + r0;                      // query0
  }
  __syncthreads();

  // ---------- Phase 3: 255 sequential decode steps ----------
  for (int step = 0; step < NSTEPS; ++step) {
    // qq = query @ Wq  (f64 accum, rounded to f32 like the materialized array)
    if (t < NH) {
      double acc = 0.0;
      for (int k = 0; k < NE; ++k)
        acc += (double)sh.m.query[k] * (double)Wq[k * NH + t];
      sh.m.qq[t] = (float)acc;
    }
    __syncthreads();  // S1

    // logits
    float logit;
    bool masked = (sh.m.maskArr[t] != 0.0f);
    if (!masked) {
      double a0 = 0.0, a1 = 0.0, a2 = 0.0, a3 = 0.0;
      const float4*  qq4 = (const float4*)sh.m.qq;
      const double2* vv2 = (const double2*)sh.m.vvd;
#pragma unroll
      for (int h4 = 0; h4 < 32; ++h4) {
        float4  q  = qq4[h4];
        double2 va = vv2[2 * h4];
        double2 vb = vv2[2 * h4 + 1];
        a0 += (double)fast_tanh(q.x + refr[4 * h4 + 0]) * va.x;
        a1 += (double)fast_tanh(q.y + refr[4 * h4 + 1]) * va.y;
        a2 += (double)fast_tanh(q.z + refr[4 * h4 + 2]) * vb.x;
        a3 += (double)fast_tanh(q.w + refr[4 * h4 + 3]) * vb.y;
      }
      float u_ = (float)((a0 + a1) + (a2 + a3));        // materialized f32
      logit = 10.0f * (float)tanh((double)u_);          // C*tanh, f32 mul
    } else {
      logit = NEGINF;
    }
    sh.m.logitArr[t] = logit;

    // gumbel g for (b, s=t), key = keys[step]
    // partitionable random_bits: (o0,o1) = tf(key, hi=0, lo=j); bits = o0^o1
    uint2 key = sh.m.keyL[step];
    uint32_t j = (uint32_t)(b256 + t);
    uint32_t o0, o1;
    tf2x32(key.x, key.y, 0u, j, o0, o1);
    uint32_t bits = o0 ^ o1;
    float f = __uint_as_float((bits >> 9) | 0x3f800000u) - 1.0f;
    float u = (f == 0.0f) ? 1.17549435e-38f : f;
    float l1 = (float)(-log((double)u));    // rounded like ref's f32 log
    float g  = (float)(-log((double)l1));
    float val = logit + g;

    double term = exp((double)logit);       // unshifted lse (logit <= 10)

    // wave reduce: argmax(val, first idx) + sum(term)
    float bv_ = val; int bi = t; double bs = term;
#pragma unroll
    for (int m = 1; m <= 32; m <<= 1) {
      float  ov = __shfl_xor(bv_, m, 64);
      int    oi = __shfl_xor(bi,  m, 64);
      double os = __shfl_xor(bs,  m, 64);
      if (ov > bv_ || (ov == bv_ && oi < bi)) { bv_ = ov; bi = oi; }
      bs += os;
    }
    int w = t >> 6;
    if ((t & 63) == 0) { sh.m.redV[w] = bv_; sh.m.redI[w] = bi; sh.m.redS[w] = bs; }
    __syncthreads();  // S2

    if (t == 0) {
      float BV = sh.m.redV[0]; int BI = sh.m.redI[0];
      for (int k = 1; k < 4; ++k) {
        float ov = sh.m.redV[k]; int oi = sh.m.redI[k];
        if (ov > BV || (ov == BV && oi < BI)) { BV = ov; BI = oi; }
      }
      double SS = ((sh.m.redS[0] + sh.m.redS[1]) + (sh.m.redS[2] + sh.m.redS[3]));
      sh.m.idxSh = BI;
      float lp = sh.m.logitArr[BI] - (float)log(SS);
      out[(size_t)b * NSTEPS + step] = (float)BI;
      out[(size_t)NBATCH * NSTEPS + (size_t)b * NSTEPS + step] = lp;
    }
    __syncthreads();  // S3

    int idx = sh.m.idxSh;
    if (t == idx) sh.m.maskArr[t] = 1.0f;
    if (t < NE) {
      float hc = cv[((size_t)b256 + idx) * NE + t];
      sh.m.hcur[t] = hc;
      if (step == 0) sh.m.inith[t] = hc;
    }
    __syncthreads();  // S4

    // query = h_bar + (concat(init_h, h) @ Wv + bv)
    if (t < NE) {
      double acc2 = 0.0;
      for (int k = 0; k < NE; ++k)
        acc2 += (double)sh.m.inith[k] * (double)Wv[k * NE + t];
      for (int k = 0; k < NE; ++k)
        acc2 += (double)sh.m.hcur[k] * (double)Wv[(NE + k) * NE + t];
      float mm = (float)acc2 + bv[t];
      sh.m.query[t] = sh.m.hbar[t] + mm;
    }
    __syncthreads();  // S5
  }
}

extern "C" void kernel_launch(void* const* d_in, const int* in_sizes, int n_in,
                              void* d_out, int out_size, void* d_ws, size_t ws_size,
                              hipStream_t stream) {
  const float* cv   = (const float*)d_in[0];
  // d_in[1] = original_node: unused by the returned outputs
  const float* mask = (const float*)d_in[2];
  const float* liw  = (const float*)d_in[3];
  const float* Wc   = (const float*)d_in[4];
  const float* bc   = (const float*)d_in[5];
  const float* Wv   = (const float*)d_in[6];
  const float* bv   = (const float*)d_in[7];
  const float* Wq   = (const float*)d_in[8];
  const float* Wref = (const float*)d_in[9];
  const float* vv   = (const float*)d_in[10];
  (void)in_sizes; (void)n_in; (void)out_size; (void)d_ws; (void)ws_size;

  decoder_kernel<<<NBATCH, 256, 0, stream>>>(cv, mask, liw, Wc, bc, Wv, bv,
                                             Wq, Wref, vv, (float*)d_out);
}

// Round 3
// 4016.499 us; speedup vs baseline: 1.4174x; 1.4174x over previous
//
#include <hip/hip_runtime.h>
#include <hip/hip_bf16.h>
#include <stdint.h>
#include <math.h>

#define NBATCH 512
#define NS 256
#define NE 128
#define NH 128
#define NSTEPS 255
#define NEGINF -1e8f

// ---------------- threefry2x32 (partitionable path, verified r2) ----------------
__device__ __forceinline__ uint32_t rotl32(uint32_t x, uint32_t r) {
  return (x << r) | (x >> (32u - r));
}

__device__ __forceinline__ void tf2x32(uint32_t k0, uint32_t k1,
                                       uint32_t x0, uint32_t x1,
                                       uint32_t& o0, uint32_t& o1) {
  uint32_t ks2 = k0 ^ k1 ^ 0x1BD11BDAu;
  x0 += k0; x1 += k1;
#define TF_R4(a,b,c,d) \
  x0 += x1; x1 = rotl32(x1,a); x1 ^= x0; \
  x0 += x1; x1 = rotl32(x1,b); x1 ^= x0; \
  x0 += x1; x1 = rotl32(x1,c); x1 ^= x0; \
  x0 += x1; x1 = rotl32(x1,d); x1 ^= x0;
  TF_R4(13,15,26,6)   x0 += k1;  x1 += ks2 + 1u;
  TF_R4(17,29,16,24)  x0 += ks2; x1 += k0 + 2u;
  TF_R4(13,15,26,6)   x0 += k0;  x1 += k1 + 3u;
  TF_R4(17,29,16,24)  x0 += k1;  x1 += ks2 + 4u;
  TF_R4(13,15,26,6)   x0 += ks2; x1 += k0 + 5u;
#undef TF_R4
  o0 = x0; o1 = x1;
}

// tanh via hw exp2 + rcp + 1 Newton step: <=1 ulp, ~half the cycles of IEEE div
__device__ __forceinline__ float nr_tanh(float x) {
  const float Chi = 2.8853900432586670f;      // float(2*log2(e))
  const float Clo = 3.8519259822379735e-08f;  // residual
  float m = fmaf(x, Chi, x * Clo);
  m = fminf(m, 126.0f);                        // avoid inf in NR (tanh==1 long before)
  float tt = __builtin_amdgcn_exp2f(m);
  float d  = tt + 1.0f;
  float r  = __builtin_amdgcn_rcpf(d);
  r = r * fmaf(-d, r, 2.0f);                   // Newton: ~correctly rounded
  return fmaf(-2.0f, r, 1.0f);
}

// ======================= precompute kernels =======================
// K1: M1T[h][e] = sum_j WvTop[e][j]*Wq[j][h]; M2T likewise for WvBot;
//     rest0[h] = f32(liw @ Wv)[h] + bv[h]
__global__ void k1_mats(const float* __restrict__ Wv, const float* __restrict__ Wq,
                        const float* __restrict__ liw, const float* __restrict__ bvv,
                        float* __restrict__ M1T, float* __restrict__ M2T,
                        float* __restrict__ rest0) {
  int e = blockIdx.x, h = threadIdx.x;
  __shared__ float wrow[NE];
  if (e < 256) {
    wrow[h] = Wv[e * NE + h];
    __syncthreads();
    double a = 0.0;
    for (int k = 0; k < NE; ++k) a += (double)wrow[k] * (double)Wq[k * NH + h];
    if (e < 128) M1T[h * NE + e] = (float)a;
    else         M2T[h * NE + (e - 128)] = (float)a;
  } else {
    double a = 0.0;
    for (int k = 0; k < 2 * NE; ++k) a += (double)liw[k] * (double)Wv[k * NE + h];
    rest0[h] = (float)a + bvv[h];
  }
}

// K2: per-b h_bar, then qqbase[b][h] = f64((hbar+bv) @ Wq), qq0[b][h] = f32((hbar+rest0) @ Wq)
__global__ void k2_base(const float* __restrict__ cv, const float* __restrict__ Wc,
                        const float* __restrict__ bc, const float* __restrict__ bvv,
                        const float* __restrict__ Wq, const float* __restrict__ rest0,
                        double* __restrict__ qqbase, float* __restrict__ qq0) {
  int b = blockIdx.x, h = threadIdx.x;
  int b256 = b << 8;
  __shared__ float meanL[NE], hbarL[NE];
  double ms = 0.0;
  for (int s = 0; s < NS; ++s) ms += (double)cv[((size_t)b256 + s) * NE + h];
  meanL[h] = (float)(ms * (1.0 / 256.0));
  __syncthreads();
  double a = 0.0;
  for (int e = 0; e < NE; ++e) a += (double)meanL[e] * (double)Wc[e * NE + h];
  hbarL[h] = (float)a + bc[h];
  __syncthreads();
  double ab = 0.0, a0 = 0.0;
  for (int k = 0; k < NE; ++k) {
    double w = (double)Wq[k * NH + h];
    ab += (double)(hbarL[k] + bvv[k]) * w;     // decomposition base
    a0 += (double)(hbarL[k] + rest0[k]) * w;   // exact step-0 query0 @ Wq
  }
  qqbase[(size_t)b * NH + h] = ab;
  qq0[(size_t)b * NH + h] = (float)a0;
}

// ======================= main decode kernel (512 thr: row s = t&255, half = t>>8) ====
struct MainSh {
  alignas(16) float  qq[NH];
  alignas(16) float  vvf[NH];
  alignas(16) float  hcur[NE];
  float  logitArr[NS];
  alignas(8) double partA[NS];
  uint2  keyL[NSTEPS];
  float  redV[4];
  float  redS[4];
  int    redI[4];
};

struct PreSh {
  float cvS[NS][33];   // padded, conflict-free per-lane rows
  float wS[32][NH];
};

__global__ __launch_bounds__(512, 4)   // 4 waves/EU -> 2 blocks/CU (16 waves)
void decode_fast(const float* __restrict__ cv,
                 const float* __restrict__ mask_in,
                 const float* __restrict__ vvec,
                 const double* __restrict__ qqbase,
                 const float* __restrict__ M1T,
                 const float* __restrict__ M2T,
                 const float* __restrict__ qq0,
                 float* __restrict__ out) {
  const int b = blockIdx.x;
  const int t = threadIdx.x;
  const int s = t & 255;
  const int half = t >> 8;
  const int hb = half << 6;        // this thread's h range: [hb, hb+64)
  const int b256 = b << 8;

  __shared__ union { PreSh pre; MainSh m; } sh;

  // ---------- Phase 1: refr[j] = ref[s][hb+j], bit-identical chunking to r2 ----------
  float refr[64];
#pragma unroll
  for (int j = 0; j < 64; ++j) refr[j] = 0.0f;

  for (int ec = 0; ec < 4; ++ec) {
    __syncthreads();
    for (int i = t; i < 32 * NH; i += 512) {
      int r = i >> 7, c = i & 127;
      sh.pre.wS[r][c] = __builtin_nontemporal_load(&cv[0]) * 0.0f +  // keep simple: plain load below
                        0.0f;
    }
    // (rewrite loads plainly)
    for (int i = t; i < 32 * NH; i += 512) {
      int r = i >> 7, c = i & 127;
      sh.pre.wS[r][c] = 0.0f;
    }
    __syncthreads();
    for (int i = t; i < 32 * NH; i += 512) {
      int r = i >> 7, c = i & 127;
      sh.pre.wS[r][c] = 0.0f;  // placeholder; real assignment below
    }
    break;  // never taken path guard (structure replaced below)
  }

  // --- real phase 1 (clean version) ---
#pragma unroll
  for (int j = 0; j < 64; ++j) refr[j] = 0.0f;
  {
    const float* Wref = vvec;  // dummy init to satisfy compiler; overwritten by arg below
  }
  // NOTE: Wref passed via global pointer below
  // (see kernel args — Wref smuggled through: we re-declare properly)
  // ---- actual implementation follows in decode_fast2; this kernel is unused ----
  (void)cv; (void)mask_in; (void)qqbase; (void)M1T; (void)M2T; (void)qq0; (void)out;
}

// Clean, real main kernel (the one actually launched)
__global__ __launch_bounds__(512, 4)
void decode_main(const float* __restrict__ cv,
                 const float* __restrict__ mask_in,
                 const float* __restrict__ Wref,
                 const float* __restrict__ vvec,
                 const double* __restrict__ qqbase,
                 const float* __restrict__ M1T,
                 const float* __restrict__ M2T,
                 const float* __restrict__ qq0,
                 float* __restrict__ out) {
  const int b = blockIdx.x;
  const int t = threadIdx.x;
  const int s = t & 255;
  const int half = t >> 8;
  const int hb = half << 6;
  const int b256 = b << 8;

  __shared__ union { PreSh pre; MainSh m; } sh;

  // ---------- Phase 1: per-thread 64-wide slice of ref = cv @ Wref ----------
  float refr[64];
#pragma unroll
  for (int j = 0; j < 64; ++j) refr[j] = 0.0f;

  for (int ec = 0; ec < 4; ++ec) {
    __syncthreads();
    for (int i = t; i < 32 * NH; i += 512) {
      int r = i >> 7, c = i & 127;
      sh.pre.wS[r][c] = Wref[(ec * 32 + r) * NH + c];
    }
    for (int i = t; i < NS * 32; i += 512) {
      int r = i >> 5, c = i & 31;
      sh.pre.cvS[r][c] = cv[((size_t)b256 + r) * NE + ec * 32 + c];
    }
    __syncthreads();
    for (int hc = 0; hc < 8; ++hc) {
      double a[8] = {0,0,0,0,0,0,0,0};
      for (int e = 0; e < 32; ++e) {
        double cd = (double)sh.pre.cvS[s][e];
        const float* wp = &sh.pre.wS[e][hb + hc * 8];
#pragma unroll
        for (int j = 0; j < 8; ++j) a[j] += cd * (double)wp[j];
      }
#pragma unroll
      for (int j = 0; j < 8; ++j) refr[hc * 8 + j] += (float)a[j];
    }
  }
  __syncthreads();  // pre dead, m live

  // ---------- Prologue ----------
  if (t < NSTEPS) {
    uint32_t o0, o1;
    tf2x32(0u, 42u, 0u, (uint32_t)t, o0, o1);
    sh.m.keyL[t] = make_uint2(o0, o1);
  }
  if (t < NH) {
    sh.m.vvf[t] = vvec[t];
    sh.m.qq[t] = qq0[(size_t)b * NH + t];
  }
  bool maskreg = (s == 0) || (mask_in[(size_t)b256 + s] > 0.0f);
  __syncthreads();

  // gumbel prefetch for step 0 (half1 threads own the row logic)
  float gnext = 0.0f;
  if (half) {
    uint2 key = sh.m.keyL[0];
    uint32_t o0, o1;
    tf2x32(key.x, key.y, 0u, (uint32_t)(b256 + s), o0, o1);
    uint32_t bits = o0 ^ o1;
    float f = __uint_as_float((bits >> 9) | 0x3f800000u) - 1.0f;
    float u = (f == 0.0f) ? 1.17549435e-38f : f;
    float l1 = -logf(u);
    gnext = -logf(l1);
  }

  double qqb2 = 0.0;  // per-(t<128) running decomposition base (f64)

  // ---------- 255 decode steps ----------
  for (int step = 0; step < NSTEPS; ++step) {
    // A: per-half tanh partial
    double a0 = 0, a1 = 0, a2 = 0, a3 = 0;
    if (!maskreg) {
      const float4* qq4 = (const float4*)(sh.m.qq + hb);
      const float4* vv4 = (const float4*)(sh.m.vvf + hb);
#pragma unroll
      for (int i = 0; i < 16; ++i) {
        float4 q = qq4[i];
        float4 w = vv4[i];
        a0 += (double)nr_tanh(q.x + refr[4 * i + 0]) * (double)w.x;
        a1 += (double)nr_tanh(q.y + refr[4 * i + 1]) * (double)w.y;
        a2 += (double)nr_tanh(q.z + refr[4 * i + 2]) * (double)w.z;
        a3 += (double)nr_tanh(q.w + refr[4 * i + 3]) * (double)w.w;
      }
    }
    double accH = (a0 + a1) + (a2 + a3);
    if (!half) sh.m.partA[s] = accH;
    __syncthreads();  // B1

    if (half) {
      float logit;
      if (!maskreg) {
        float u_ = (float)(sh.m.partA[s] + accH);
        logit = 10.0f * (float)tanh((double)u_);
      } else {
        logit = NEGINF;
      }
      sh.m.logitArr[s] = logit;
      float term = __expf(0.0f) == 1.0f ? expf(logit) : expf(logit);  // plain expf
      float val = logit + gnext;

      float bvv = val; int bii = s; float bss = term;
#pragma unroll
      for (int mm = 1; mm <= 32; mm <<= 1) {
        float ov = __shfl_xor(bvv, mm, 64);
        int   oi = __shfl_xor(bii, mm, 64);
        float os = __shfl_xor(bss, mm, 64);
        bss += os;
        if (ov > bvv || (ov == bvv && oi < bii)) { bvv = ov; bii = oi; }
      }
      if ((t & 63) == 0) {
        int w = (t >> 6) - 4;
        sh.m.redV[w] = bvv; sh.m.redI[w] = bii; sh.m.redS[w] = bss;
      }
    }
    __syncthreads();  // B2

    // everyone: final argmax over 4 wave partials
    float BV = sh.m.redV[0]; int BI = sh.m.redI[0];
#pragma unroll
    for (int k = 1; k < 4; ++k) {
      float ov = sh.m.redV[k]; int oi = sh.m.redI[k];
      if (ov > BV || (ov == BV && oi < BI)) { BV = ov; BI = oi; }
    }
    if (s == BI) maskreg = true;

    if (t == 256) {
      double SS = (double)((sh.m.redS[0] + sh.m.redS[1]) + (sh.m.redS[2] + sh.m.redS[3]));
      float lp = sh.m.logitArr[BI] - (float)log(SS);
      out[(size_t)b * NSTEPS + step] = (float)BI;
      out[(size_t)NBATCH * NSTEPS + (size_t)b * NSTEPS + step] = lp;
    }
    if (t < NE) sh.m.hcur[t] = cv[((size_t)b256 + BI) * NE + t];
    __syncthreads();  // B3 (hcur ready)

    if (t < 128) {
      const float4* hc4 = (const float4*)sh.m.hcur;
      if (step == 0) {
        double a = qqbase[(size_t)b * NH + t];
        const float4* m1 = (const float4*)(M1T + (size_t)t * NE);
#pragma unroll 8
        for (int i = 0; i < 32; ++i) {
          float4 hv = hc4[i]; float4 mm = m1[i];
          a += (double)hv.x * (double)mm.x + (double)hv.y * (double)mm.y
             + (double)hv.z * (double)mm.z + (double)hv.w * (double)mm.w;
        }
        qqb2 = a;
      }
      double a = qqb2;
      const float4* m2 = (const float4*)(M2T + (size_t)t * NE);
#pragma unroll 8
      for (int i = 0; i < 32; ++i) {
        float4 hv = hc4[i]; float4 mm = m2[i];
        a += (double)hv.x * (double)mm.x + (double)hv.y * (double)mm.y
           + (double)hv.z * (double)mm.z + (double)hv.w * (double)mm.w;
      }
      sh.m.qq[t] = (float)a;
    } else if (half && step + 1 < NSTEPS) {
      // overlap next-step gumbel with the qq matmul
      uint2 key = sh.m.keyL[step + 1];
      uint32_t o0, o1;
      tf2x32(key.x, key.y, 0u, (uint32_t)(b256 + s), o0, o1);
      uint32_t bits = o0 ^ o1;
      float f = __uint_as_float((bits >> 9) | 0x3f800000u) - 1.0f;
      float u = (f == 0.0f) ? 1.17549435e-38f : f;
      float l1 = -logf(u);
      gnext = -logf(l1);
    }
    __syncthreads();  // B4 (qq ready)
  }
}

// ======================= round-2 passing kernel (fallback if ws too small) ==========
__device__ __forceinline__ float fast_tanh_ref(float x) {
  const float Chi = 2.8853900432586670f;
  const float Clo = 3.8519259822379735e-08f;
  float m = fmaf(x, Chi, x * Clo);
  float tt = exp2f(m);
  return 1.0f - 2.0f / (tt + 1.0f);
}

struct MainShR {
  float  query[NE];
  float  qq[NH];
  float  hbar[NE];
  float  inith[NE];
  float  hcur[NE];
  alignas(16) double vvd[NH];
  float  logitArr[NS];
  float  maskArr[NS];
  uint2  keyL[NSTEPS];
  float  meanv[NE];
  float  redV[4];
  int    redI[4];
  double redS[4];
  int    idxSh;
};
struct PreShR {
  float cvS[NS][33];
  float wS[32][NH];
};

__global__ __launch_bounds__(256, 2)
void decoder_kernel_ref(const float* __restrict__ cv, const float* __restrict__ mask_in,
                        const float* __restrict__ liw, const float* __restrict__ Wc,
                        const float* __restrict__ bc, const float* __restrict__ Wv,
                        const float* __restrict__ bv, const float* __restrict__ Wq,
                        const float* __restrict__ Wref, const float* __restrict__ vvec,
                        float* __restrict__ out) {
  const int b = blockIdx.x;
  const int t = threadIdx.x;
  const int b256 = b << 8;
  __shared__ union { PreShR pre; MainShR m; } sh;

  float refr[NH];
#pragma unroll
  for (int h = 0; h < NH; ++h) refr[h] = 0.0f;
  for (int ec = 0; ec < 4; ++ec) {
    const int e0 = ec * 32;
    __syncthreads();
    for (int i = t; i < 32 * NH; i += 256) {
      int r = i >> 7, h = i & 127;
      sh.pre.wS[r][h] = Wref[(e0 + r) * NH + h];
    }
    for (int i = t; i < NS * 32; i += 256) {
      int s2 = i >> 5, j = i & 31;
      sh.pre.cvS[s2][j] = cv[((size_t)b256 + s2) * NE + e0 + j];
    }
    __syncthreads();
#pragma unroll
    for (int hc = 0; hc < 16; ++hc) {
      double a[8] = {0,0,0,0,0,0,0,0};
      for (int e = 0; e < 32; ++e) {
        double cd = (double)sh.pre.cvS[t][e];
#pragma unroll
        for (int j = 0; j < 8; ++j) a[j] += cd * (double)sh.pre.wS[e][hc * 8 + j];
      }
#pragma unroll
      for (int j = 0; j < 8; ++j) refr[hc * 8 + j] += (float)a[j];
    }
  }
  __syncthreads();

  if (t < NSTEPS) {
    uint32_t o0, o1;
    tf2x32(0u, 42u, 0u, (uint32_t)t, o0, o1);
    sh.m.keyL[t] = make_uint2(o0, o1);
  }
  if (t < NH) sh.m.vvd[t] = (double)vvec[t];
  sh.m.maskArr[t] = (mask_in[(size_t)b256 + t] > 0.0f || t == 0) ? 1.0f : 0.0f;
  if (t < NE) {
    double s64 = 0.0;
    for (int s2 = 0; s2 < NS; ++s2) s64 += (double)cv[((size_t)b256 + s2) * NE + t];
    sh.m.meanv[t] = (float)(s64 * (1.0 / 256.0));
  }
  __syncthreads();
  if (t < NE) {
    double acc = 0.0;
    for (int e = 0; e < NE; ++e) acc += (double)sh.m.meanv[e] * (double)Wc[e * NE + t];
    float hbv = (float)acc + bc[t];
    sh.m.hbar[t] = hbv;
    double acc2 = 0.0;
    for (int k = 0; k < 2 * NE; ++k) acc2 += (double)liw[k] * (double)Wv[k * NE + t];
    float r0 = (float)acc2 + bv[t];
    sh.m.query[t] = hbv + r0;
  }
  __syncthreads();

  for (int step = 0; step < NSTEPS; ++step) {
    if (t < NH) {
      double acc = 0.0;
      for (int k = 0; k < NE; ++k) acc += (double)sh.m.query[k] * (double)Wq[k * NH + t];
      sh.m.qq[t] = (float)acc;
    }
    __syncthreads();

    float logit;
    bool masked = (sh.m.maskArr[t] != 0.0f);
    if (!masked) {
      double a0 = 0.0, a1 = 0.0, a2 = 0.0, a3 = 0.0;
      const float4*  qq4 = (const float4*)sh.m.qq;
      const double2* vv2 = (const double2*)sh.m.vvd;
#pragma unroll
      for (int h4 = 0; h4 < 32; ++h4) {
        float4  q  = qq4[h4];
        double2 va = vv2[2 * h4];
        double2 vb = vv2[2 * h4 + 1];
        a0 += (double)fast_tanh_ref(q.x + refr[4 * h4 + 0]) * va.x;
        a1 += (double)fast_tanh_ref(q.y + refr[4 * h4 + 1]) * va.y;
        a2 += (double)fast_tanh_ref(q.z + refr[4 * h4 + 2]) * vb.x;
        a3 += (double)fast_tanh_ref(q.w + refr[4 * h4 + 3]) * vb.y;
      }
      float u_ = (float)((a0 + a1) + (a2 + a3));
      logit = 10.0f * (float)tanh((double)u_);
    } else {
      logit = NEGINF;
    }
    sh.m.logitArr[t] = logit;

    uint2 key = sh.m.keyL[step];
    uint32_t j = (uint32_t)(b256 + t);
    uint32_t o0, o1;
    tf2x32(key.x, key.y, 0u, j, o0, o1);
    uint32_t bits = o0 ^ o1;
    float f = __uint_as_float((bits >> 9) | 0x3f800000u) - 1.0f;
    float u = (f == 0.0f) ? 1.17549435e-38f : f;
    float l1 = (float)(-log((double)u));
    float g  = (float)(-log((double)l1));
    float val = logit + g;
    double term = exp((double)logit);

    float bv_ = val; int bi = t; double bs = term;
#pragma unroll
    for (int m = 1; m <= 32; m <<= 1) {
      float  ov = __shfl_xor(bv_, m, 64);
      int    oi = __shfl_xor(bi,  m, 64);
      double os = __shfl_xor(bs,  m, 64);
      if (ov > bv_ || (ov == bv_ && oi < bi)) { bv_ = ov; bi = oi; }
      bs += os;
    }
    int w = t >> 6;
    if ((t & 63) == 0) { sh.m.redV[w] = bv_; sh.m.redI[w] = bi; sh.m.redS[w] = bs; }
    __syncthreads();

    if (t == 0) {
      float BV = sh.m.redV[0]; int BI = sh.m.redI[0];
      for (int k = 1; k < 4; ++k) {
        float ov = sh.m.redV[k]; int oi = sh.m.redI[k];
        if (ov > BV || (ov == BV && oi < BI)) { BV = ov; BI = oi; }
      }
      double SS = ((sh.m.redS[0] + sh.m.redS[1]) + (sh.m.redS[2] + sh.m.redS[3]));
      sh.m.idxSh = BI;
      float lp = sh.m.logitArr[BI] - (float)log(SS);
      out[(size_t)b * NSTEPS + step] = (float)BI;
      out[(size_t)NBATCH * NSTEPS + (size_t)b * NSTEPS + step] = lp;
    }
    __syncthreads();

    int idx = sh.m.idxSh;
    if (t == idx) sh.m.maskArr[t] = 1.0f;
    if (t < NE) {
      float hc = cv[((size_t)b256 + idx) * NE + t];
      sh.m.hcur[t] = hc;
      if (step == 0) sh.m.inith[t] = hc;
    }
    __syncthreads();

    if (t < NE) {
      double acc2 = 0.0;
      for (int k = 0; k < NE; ++k) acc2 += (double)sh.m.inith[k] * (double)Wv[k * NE + t];
      for (int k = 0; k < NE; ++k) acc2 += (double)sh.m.hcur[k] * (double)Wv[(NE + k) * NE + t];
      float mm = (float)acc2 + bv[t];
      sh.m.query[t] = sh.m.hbar[t] + mm;
    }
    __syncthreads();
  }
}

extern "C" void kernel_launch(void* const* d_in, const int* in_sizes, int n_in,
                              void* d_out, int out_size, void* d_ws, size_t ws_size,
                              hipStream_t stream) {
  const float* cv   = (const float*)d_in[0];
  const float* mask = (const float*)d_in[2];
  const float* liw  = (const float*)d_in[3];
  const float* Wc   = (const float*)d_in[4];
  const float* bc   = (const float*)d_in[5];
  const float* Wv   = (const float*)d_in[6];
  const float* bv   = (const float*)d_in[7];
  const float* Wq   = (const float*)d_in[8];
  const float* Wref = (const float*)d_in[9];
  const float* vv   = (const float*)d_in[10];
  (void)in_sizes; (void)n_in; (void)out_size;

  const size_t SZ_QQB = (size_t)NBATCH * NH * sizeof(double);  // 512 KB
  const size_t SZ_M   = (size_t)NE * NH * sizeof(float);       // 64 KB each
  const size_t SZ_QQ0 = (size_t)NBATCH * NH * sizeof(float);   // 256 KB
  const size_t need = SZ_QQB + 2 * SZ_M + SZ_QQ0 + 512;

  if (ws_size >= need) {
    char* p = (char*)d_ws;
    double* qqbase = (double*)p;            p += SZ_QQB;
    float*  M1T    = (float*)p;             p += SZ_M;
    float*  M2T    = (float*)p;             p += SZ_M;
    float*  qq0    = (float*)p;             p += SZ_QQ0;
    float*  rest0  = (float*)p;

    k1_mats<<<257, 128, 0, stream>>>(Wv, Wq, liw, bv, M1T, M2T, rest0);
    k2_base<<<NBATCH, 128, 0, stream>>>(cv, Wc, bc, bv, Wq, rest0, qqbase, qq0);
    decode_main<<<NBATCH, 512, 0, stream>>>(cv, mask, Wref, vv, qqbase, M1T, M2T,
                                            qq0, (float*)d_out);
  } else {
    decoder_kernel_ref<<<NBATCH, 256, 0, stream>>>(cv, mask, liw, Wc, bc, Wv, bv,
                                                   Wq, Wref, vv, (float*)d_out);
  }
}